// Round 16
// baseline (333.940 us; speedup 1.0000x reference)
//
#include <hip/hip_runtime.h>
#include <math.h>

#define B_ 16
#define S_ 1024
#define D_ 512
#define H_ 4
#define INV_TEMP 0.044194173824159216f   // 1/sqrt(512)
#define C_SCALE 0.00390625f              // 2^-8: keeps head-4 scores inside fp16 range
#define OUT_SCALE 256.0f

typedef _Float16 f16;
typedef _Float16 f16x8 __attribute__((ext_vector_type(8)));
typedef _Float16 f16x4 __attribute__((ext_vector_type(4)));
typedef float f32x4 __attribute__((ext_vector_type(4)));

#define AS1(p) ((const __attribute__((address_space(1))) void*)(p))
#define AS3(p) ((__attribute__((address_space(3))) void*)(p))
#define MFMA __builtin_amdgcn_mfma_f32_16x16x32_f16

// raw barrier + sched fences (phase boundaries pinned; NO implicit vmcnt drain)
#define SBAR()                                                                 \
    do {                                                                       \
        __builtin_amdgcn_sched_barrier(0);                                     \
        __builtin_amdgcn_s_barrier();                                          \
        __builtin_amdgcn_sched_barrier(0);                                     \
    } while (0)
#define VMF(N)                                                                 \
    do {                                                                       \
        __builtin_amdgcn_sched_barrier(0);                                     \
        asm volatile("s_waitcnt vmcnt(" #N ")" ::: "memory");                  \
        __builtin_amdgcn_sched_barrier(0);                                     \
    } while (0)

// opaque LDS read: compiler can't see the LDS dependence -> it cannot insert
// its own vmcnt(0) drain before it (the r7 failure mode). Ordered manually
// with VMF/SBAR/lgkmcnt. Proven r15 (+9.2 us on k_vs).
__device__ __forceinline__ f16x8 ds_rd16(unsigned addr)
{
    f16x8 r;
    asm volatile("ds_read_b128 %0, %1" : "=v"(r) : "v"(addr));
    return r;
}

// ===========================================================================
// Fused prologue (single launch, 9281 blocks x 256 thr) — round-14 proven.
// ===========================================================================
__global__ __launch_bounds__(256)
void k_pre(const float* __restrict__ x0, f16* __restrict__ xh,
           const float* __restrict__ W, f16* __restrict__ Wh,
           const int* __restrict__ etype, int* __restrict__ flag,
           float* __restrict__ ssb)
{
    const int t = threadIdx.x;
    const int bi = blockIdx.x;
    if (bi < 8192) {
        const int xcd = bi & 7, j = bi >> 3;          // j in [0,1024)
        const int b = 2 * xcd + (j & 1);
        const int off = j >> 1;                       // [0,512) chunks/batch
        const int i = (b * 512 + off) * 256 + t;      // float4 index
        const float4 v = ((const float4*)x0)[i];
        f16x4 h; h[0] = (f16)v.x; h[1] = (f16)v.y; h[2] = (f16)v.z; h[3] = (f16)v.w;
        ((f16x4*)xh)[i] = h;
    } else if (bi < 9216) {
        const int i = (bi - 8192) * 256 + t;
        const float4 v = ((const float4*)W)[i];
        f16x4 h; h[0] = (f16)v.x; h[1] = (f16)v.y; h[2] = (f16)v.z; h[3] = (f16)v.w;
        ((f16x4*)Wh)[i] = h;
    } else if (bi == 9216) {
        if (t < 128) {
            const int b = t >> 3, kt = t & 7;
            const int* p = etype + b * S_ + kt * 128;
            int any0 = 0;
#pragma unroll
            for (int i = 0; i < 128; i += 4) {
                const int4 v = *(const int4*)(p + i);
                any0 |= (v.x == 0) | (v.y == 0) | (v.z == 0) | (v.w == 0);
            }
            flag[t] = any0;
        }
    } else {
        const int i = (bi - 9217) * 256 + t;     // 64 blocks cover 16K float4
        ((float4*)ssb)[i] = make_float4(0.f, 0.f, 0.f, 0.f);
    }
}

// ---------------------------------------------------------------------------
// 256-thread stage: 128 rows x 64 f16 (16 KB), 4 gload_lds/thread, linear
// dest + pre-swizzled global source (16B slot s of row r <- col-group
// s ^ (r&7); proven zero-conflict r10).
// ---------------------------------------------------------------------------
__device__ __forceinline__ void stage128x64(const f16* __restrict__ src, int ld,
                                            char* lds0, int t)
{
    const int r = t >> 3;                         // [0,32)
    const int c = ((t & 7) ^ (r & 7)) << 3;
    const f16* g = src + (size_t)r * ld + c;
#pragma unroll
    for (int j = 0; j < 4; ++j)                   // (r+32j)&7 == r&7
        __builtin_amdgcn_global_load_lds(AS1(g + (size_t)(32 * j) * ld),
                                         AS3(lds0 + j * 4096 + t * 16), 16, 0, 0);
}

// asm-read MMA for one K=64 step (kk-outer order preserved -> bitwise-same).
__device__ __forceinline__ void mma_asm(unsigned aB, unsigned bB,
                                        const unsigned (*offA)[2],
                                        const unsigned (*offB)[2],
                                        f32x4 (*acc)[4])
{
    f16x8 af[4][2], bf[4][2];
#pragma unroll
    for (int kk = 0; kk < 2; ++kk) {
#pragma unroll
        for (int i = 0; i < 4; ++i) af[i][kk] = ds_rd16(aB + offA[i][kk]);
#pragma unroll
        for (int j = 0; j < 4; ++j) bf[j][kk] = ds_rd16(bB + offB[j][kk]);
    }
    asm volatile("s_waitcnt lgkmcnt(0)" ::: "memory");
    __builtin_amdgcn_sched_barrier(0);            // rule #18: pin MFMA after wait
#pragma unroll
    for (int kk = 0; kk < 2; ++kk)
#pragma unroll
        for (int i = 0; i < 4; ++i)
#pragma unroll
            for (int j = 0; j < 4; ++j)
                acc[i][j] = MFMA(af[i][kk], bf[j][kk], acc[i][j], 0, 0, 0);
}

// ---------------------------------------------------------------------------
// Counted-vmcnt double-buffered GEMM, K=512 fixed (k_vs). Proven r15.
// Per step: stage(next buf) -> VMF(8) -> SBAR -> mma_asm(cur) -> SBAR.
// Ledger (8 gload_lds/stage/wave): outstanding peaks at 16; VMF(8) retires
// exactly the previously-staged buffer; SBAR makes it cross-wave; VMF(0)
// only at tail. Buffers compile-time (r4 lesson). LDS 64KB -> 2 blocks/CU.
// ---------------------------------------------------------------------------
__device__ __forceinline__ void gemm_cnt(const f16* __restrict__ A, int ldA,
                                         const f16* __restrict__ Bm, int ldB,
                                         char* lds, int t,
                                         const unsigned (*offA)[2],
                                         const unsigned (*offB)[2],
                                         f32x4 (*acc)[4])
{
    const unsigned base = (unsigned)(unsigned long long)AS3(lds);
    // X: A@+0 B@+16384 | Y: A@+32768 B@+49152
    stage128x64(A, ldA, lds, t);
    stage128x64(Bm, ldB, lds + 16384, t);
#pragma unroll 1
    for (int i = 0; i < 3; ++i) {
        const int k1 = i * 128 + 64, k2 = i * 128 + 128;
        stage128x64(A + k1, ldA, lds + 32768, t);
        stage128x64(Bm + k1, ldB, lds + 49152, t);
        VMF(8); SBAR();
        mma_asm(base, base + 16384, offA, offB, acc);        // k = 128i
        SBAR();
        stage128x64(A + k2, ldA, lds, t);
        stage128x64(Bm + k2, ldB, lds + 16384, t);
        VMF(8); SBAR();
        mma_asm(base + 32768, base + 49152, offA, offB, acc); // k = 128i+64
        SBAR();
    }
    stage128x64(A + 448, ldA, lds + 32768, t);
    stage128x64(Bm + 448, ldB, lds + 49152, t);
    VMF(8); SBAR();
    mma_asm(base, base + 16384, offA, offB, acc);             // k = 384
    SBAR();
    VMF(0); SBAR();
    mma_asm(base + 32768, base + 49152, offA, offB, acc);     // k = 448
}

// ===========================================================================
// k_vs: EXACT round-15 proven version (counted-vmcnt, 128x128, 4 waves):
//   blocks [0,1024): scores (XCD-pinned, ~44% early-exit) + fused Sum(s^2)
//   blocks [1024,1536): vT = ELU(x @ W^T + b)^T, XCD-pinned
// ===========================================================================
__global__ __launch_bounds__(256)
void k_vs(const f16* __restrict__ xh, const f16* __restrict__ Wh,
          const float* __restrict__ bias, f16* __restrict__ vT,
          const int* __restrict__ etype, const int* __restrict__ flag,
          f16* __restrict__ sh, float* __restrict__ ss)
{
    __shared__ __align__(16) char lds[65536];
    const int t = threadIdx.x;
    const int w = t >> 6, lane = t & 63, lr = lane & 15, quad = lane >> 4;
    const int wm = w & 1, wn = w >> 1;

    unsigned offA[4][2], offB[4][2];
#pragma unroll
    for (int i = 0; i < 4; ++i) {
        const int ra = wm * 64 + i * 16 + lr;
        const int rb = wn * 64 + i * 16 + lr;
#pragma unroll
        for (int kk = 0; kk < 2; ++kk) {
            offA[i][kk] = (unsigned)((ra << 7) + ((((kk << 2) + quad) ^ (ra & 7)) << 4));
            offB[i][kk] = (unsigned)((rb << 7) + ((((kk << 2) + quad) ^ (rb & 7)) << 4));
        }
    }

    if (blockIdx.x < 1024) {
        // ---------------- scores ----------------
        const int i0 = blockIdx.x;
        const int xcd = i0 & 7, j0 = i0 >> 3;          // j0 in [0,128)
        const int b = 2 * xcd + (j0 & 1);
        const int tile = j0 >> 1;                      // [0,64)
        const int bk = (tile & 7) * 128;               // keys (M)
        const int bq = (tile >> 3) * 128;              // queries (N)
        if (bk < bq && !flag[b * 8 + (bk >> 7)]) return;

        const f16* xb = xh + (size_t)b * S_ * D_;
        f32x4 acc[4][4] = {};
        gemm_cnt(xb + (size_t)bk * D_, D_, xb + (size_t)bq * D_, D_,
                 lds, t, offA, offB, acc);
        const float sc = INV_TEMP * C_SCALE;
        float ssq[4] = {0.0f, 0.0f, 0.0f, 0.0f};
#pragma unroll
        for (int i = 0; i < 4; ++i) {
            const int k4 = bk + wm * 64 + i * 16 + quad * 4;
            const int4 et = *(const int4*)(etype + b * S_ + k4);
            const int ev[4] = {et.x, et.y, et.z, et.w};
#pragma unroll
            for (int j = 0; j < 4; ++j) {
                const int q = bq + wn * 64 + j * 16 + lr;
                f16x4 hv;
#pragma unroll
                for (int r = 0; r < 4; ++r) {
                    const bool keep = ((k4 + r) > q) || (ev[r] == 0);
                    hv[r] = (f16)(keep ? acc[i][j][r] * sc : 0.0f);
                    const float fv = (float)hv[r];
                    ssq[j] += fv * fv;               // sum of squares of STORED fp16
                }
                *(f16x4*)(sh + ((size_t)b * S_ + q) * S_ + k4) = hv;
            }
        }
#pragma unroll
        for (int j = 0; j < 4; ++j) {
            float v = ssq[j];
            v += __shfl_xor(v, 16, 64);
            v += __shfl_xor(v, 32, 64);
            if (quad == 0) {
                const int q = bq + wn * 64 + j * 16 + lr;
                atomicAdd(ss + b * S_ + q, v);
            }
        }
    } else {
        // -------- vT = ELU(x @ W^T + b)^T, XCD-pinned by batch --------
        const int idx = blockIdx.x - 1024;             // [0,512)
        const int xcd = idx & 7;
        const int b = 2 * xcd + ((idx >> 3) & 1);
        const int rest = idx >> 4;                     // [0,32)
        const int sq = rest & 7;                       // m-tile within batch
        const int bn = (rest >> 3) * 128;              // e-tile
        const int bm = b * 1024 + sq * 128;
        f32x4 acc[4][4] = {};
        gemm_cnt(xh + (size_t)bm * D_, D_, Wh + (size_t)bn * D_, D_,
                 lds, t, offA, offB, acc);
#pragma unroll
        for (int j = 0; j < 4; ++j) {
            const int e = bn + wn * 64 + j * 16 + lr;
            const float be = bias[e];
#pragma unroll
            for (int i = 0; i < 4; ++i) {
                const int s = sq * 128 + wm * 64 + i * 16 + quad * 4;
                f16x4 hv;
#pragma unroll
                for (int r = 0; r < 4; ++r) {
                    float z = acc[i][j][r] + be;
                    z = (z > 0.0f) ? z : (expf(z) - 1.0f);
                    hv[r] = (f16)z;
                }
                *(f16x4*)(vT + ((size_t)b * D_ + e) * S_ + s) = hv;
            }
        }
    }
}

// ===========================================================================
// k_out: counted-vmcnt port (r15 recipe). 512 blocks x 256 thr / 4 waves,
// single group (two-group combine no longer needed: pipeline hides the
// stage latency that low residency used to expose). Dynamic-length counted
// loop over kept 64-wide K offsets; ns in [2,16], block-uniform -> barrier
// count uniform. Ledger identical to gemm_cnt. K pure ascending order.
// Epilogue variants (host-selected):
//   big mode, h<3 : write per-head fp16 x-buffer only (no out traffic)
//   big mode, h==3: out = xh0 + xh1 + xh2 + xnew (single fp32 write)
//   fallback      : fp32 out RMW + xh write
// ===========================================================================
__global__ __launch_bounds__(256)
void k_out(const f16* __restrict__ vT, const f16* __restrict__ sh,
           const float* __restrict__ ss, const int* __restrict__ flag,
           f16* __restrict__ xh_w,
           const f16* __restrict__ xs0, const f16* __restrict__ xs1,
           const f16* __restrict__ xs2,
           float* __restrict__ out, const int accum, const int wout)
{
    __shared__ __align__(16) char lds[65536];   // X: A@0 B@16384 | Y: A@32768 B@49152
    __shared__ int k64[16];
    __shared__ int nsteps;
    const int t = threadIdx.x;
    const int w = t >> 6, lane = t & 63, lr = lane & 15, quad = lane >> 4;
    const int wm = w & 1, wn = w >> 1;
    const int i0 = blockIdx.x;
    const int xcd = i0 & 7, j0 = i0 >> 3;       // j0 in [0,64)
    const int b = 2 * xcd + (j0 & 1);
    const int tile = j0 >> 1;                   // [0,32)
    const int be = (tile & 3) * 128;            // e (M), fastest
    const int bq = (tile >> 2) * 128;           // q (N)
    const int qt = bq >> 7;

    if (t == 0) {
        int n = 0;
        for (int kc = 0; kc < 8; ++kc)
            if (kc >= qt || flag[b * 8 + kc]) { // kept chunk -> two 64-steps
                k64[n]     = kc * 128;
                k64[n + 1] = kc * 128 + 64;
                n += 2;
            }
        nsteps = n;                             // even, in [2,16]
    }
    __syncthreads();
    const int ns = nsteps;

    unsigned offA[4][2], offB[4][2];
#pragma unroll
    for (int i = 0; i < 4; ++i) {
        const int ra = wm * 64 + i * 16 + lr;
        const int rb = wn * 64 + i * 16 + lr;
#pragma unroll
        for (int kk = 0; kk < 2; ++kk) {
            offA[i][kk] = (unsigned)((ra << 7) + ((((kk << 2) + quad) ^ (ra & 7)) << 4));
            offB[i][kk] = (unsigned)((rb << 7) + ((((kk << 2) + quad) ^ (rb & 7)) << 4));
        }
    }

    const unsigned base = (unsigned)(unsigned long long)AS3(lds);
    const f16* Abase = vT + ((size_t)b * D_ + be) * S_;
    const f16* Bbase = sh + ((size_t)b * S_ + bq) * S_;
    f32x4 acc[4][4] = {};

    stage128x64(Abase + k64[0], S_, lds, t);
    stage128x64(Bbase + k64[0], S_, lds + 16384, t);
    int i = 1;
#pragma unroll 1
    for (; i + 1 < ns; i += 2) {
        const int ka = k64[i], kb = k64[i + 1];
        stage128x64(Abase + ka, S_, lds + 32768, t);
        stage128x64(Bbase + ka, S_, lds + 49152, t);
        VMF(8); SBAR();
        mma_asm(base, base + 16384, offA, offB, acc);
        SBAR();
        stage128x64(Abase + kb, S_, lds, t);
        stage128x64(Bbase + kb, S_, lds + 16384, t);
        VMF(8); SBAR();
        mma_asm(base + 32768, base + 49152, offA, offB, acc);
        SBAR();
    }
    if (i < ns) {                               // ns even: one step left in Y
        const int ka = k64[i];
        stage128x64(Abase + ka, S_, lds + 32768, t);
        stage128x64(Bbase + ka, S_, lds + 49152, t);
        VMF(8); SBAR();
        mma_asm(base, base + 16384, offA, offB, acc);
        SBAR();
        VMF(0); SBAR();
        mma_asm(base + 32768, base + 49152, offA, offB, acc);
    } else {                                    // ns odd: X holds the last step
        VMF(0); SBAR();
        mma_asm(base, base + 16384, offA, offB, acc);
    }

#pragma unroll
    for (int j = 0; j < 4; ++j) {
        const int q = bq + wn * 64 + j * 16 + lr;
        const float ssv = ss[b * S_ + q];
        const float scl = 1.0f / (C_SCALE * fmaxf(sqrtf(ssv) * OUT_SCALE, 1e-5f));
#pragma unroll
        for (int i2 = 0; i2 < 4; ++i2) {
            const int e4 = be + wm * 64 + i2 * 16 + quad * 4;
            const size_t o = ((size_t)b * S_ + q) * D_ + e4;
            f32x4 val;
            f16x4 hx;
#pragma unroll
            for (int r = 0; r < 4; ++r) {
                val[r] = acc[i2][j][r] * scl;
                hx[r] = (f16)val[r];
            }
            if (xh_w) *(f16x4*)(xh_w + o) = hx;
            if (xs0) {                          // final head: sum fp16 partials
                const f16x4 a0 = *(const f16x4*)(xs0 + o);
                const f16x4 a1 = *(const f16x4*)(xs1 + o);
                const f16x4 a2 = *(const f16x4*)(xs2 + o);
#pragma unroll
                for (int r = 0; r < 4; ++r)
                    val[r] += (float)a0[r] + (float)a1[r] + (float)a2[r];
            }
            if (wout) {
                f32x4 v2 = val;
                if (accum) { const f32x4 old = *(const f32x4*)(out + o); v2 = v2 + old; }
                *(f32x4*)(out + o) = v2;
            }
        }
    }
}

// ---------------------------------------------------------------------------
// Workspace (big mode, ~100.3 MB):
//   xA @0 (16M: conv output, then reused as xh0), vT @16M (16M),
//   sh @32M (32M), Wh @64M (2M), ss @66M (256K), flags @66M+256K,
//   xB @68M (16M: xh1), xC @84M (16M: xh2)
// Fallback (< 101 MB ws): xB=xC=xA, fp32 out RMW.
// ---------------------------------------------------------------------------
extern "C" void kernel_launch(void* const* d_in, const int* in_sizes, int n_in,
                              void* d_out, int out_size, void* d_ws, size_t ws_size,
                              hipStream_t stream) {
    const float* x0    = (const float*)d_in[0];
    const int*   etype = (const int*)d_in[2];
    const float* W     = (const float*)d_in[3];
    const float* bias  = (const float*)d_in[4];
    float* out = (float*)d_out;

    char* ws = (char*)d_ws;
    f16*   xA    = (f16*)(ws);
    f16*   vT    = (f16*)(ws + (16u << 20));
    f16*   sh    = (f16*)(ws + (32u << 20));
    f16*   Wh    = (f16*)(ws + (64u << 20));
    float* ssb   = (float*)(ws + (66u << 20));
    int*   flags = (int*)(ws + (66u << 20) + 262144);

    const bool big = ws_size >= ((size_t)101 << 20);
    f16* xB = big ? (f16*)(ws + (68u << 20)) : xA;
    f16* xC = big ? (f16*)(ws + (84u << 20)) : xA;

    // fused prologue: x conv + W conv + flags + ss zeroing in ONE launch
    k_pre<<<9281, 256, 0, stream>>>(x0, xA, W, Wh, etype, flags, ssb);

    // per-head k_vs input and k_out fp16 destination
    f16* xin[H_]  = {xA, xA, xB, xC};
    f16* xdst[H_] = {xA, xB, xC, nullptr};

    for (int h = 0; h < H_; ++h) {
        float* ss = ssb + (size_t)h * B_ * S_;
        k_vs <<<1536, 256, 0, stream>>>(xin[h], Wh + (size_t)h * D_ * D_,
                                        bias + (size_t)h * D_, vT,
                                        etype, flags, sh, ss);
        if (big) {
            const bool last = (h == H_ - 1);
            k_out<<<512, 256, 0, stream>>>(vT, sh, ss, flags, xdst[h],
                                           last ? xA : nullptr,
                                           last ? xB : nullptr,
                                           last ? xC : nullptr,
                                           out, 0, last ? 1 : 0);
        } else {
            k_out<<<512, 256, 0, stream>>>(vT, sh, ss, flags,
                                           (h < H_ - 1) ? xA : nullptr,
                                           nullptr, nullptr, nullptr,
                                           out, h > 0, 1);
        }
    }
}

// Round 18
// 326.551 us; speedup vs baseline: 1.0226x; 1.0226x over previous
//
#include <hip/hip_runtime.h>
#include <math.h>

#define B_ 16
#define S_ 1024
#define D_ 512
#define H_ 4
#define INV_TEMP 0.044194173824159216f   // 1/sqrt(512)
#define C_SCALE 0.00390625f              // 2^-8: keeps head-4 scores inside fp16 range
#define OUT_SCALE 256.0f

typedef _Float16 f16;
typedef _Float16 f16x8 __attribute__((ext_vector_type(8)));
typedef _Float16 f16x4 __attribute__((ext_vector_type(4)));
typedef float f32x4 __attribute__((ext_vector_type(4)));

#define AS1(p) ((const __attribute__((address_space(1))) void*)(p))
#define AS3(p) ((__attribute__((address_space(3))) void*)(p))
#define MFMA __builtin_amdgcn_mfma_f32_16x16x32_f16

// raw barrier + sched fences (phase boundaries pinned; NO implicit vmcnt drain)
#define SBAR()                                                                 \
    do {                                                                       \
        __builtin_amdgcn_sched_barrier(0);                                     \
        __builtin_amdgcn_s_barrier();                                          \
        __builtin_amdgcn_sched_barrier(0);                                     \
    } while (0)
#define VMF(N)                                                                 \
    do {                                                                       \
        __builtin_amdgcn_sched_barrier(0);                                     \
        asm volatile("s_waitcnt vmcnt(" #N ")" ::: "memory");                  \
        __builtin_amdgcn_sched_barrier(0);                                     \
    } while (0)

// opaque LDS read: compiler can't see the LDS dependence -> it cannot insert
// its own vmcnt(0) drain before it (the r7 failure mode). Ordered manually
// with VMF/SBAR/lgkmcnt. Proven r15 (+9.2 us on k_vs).
__device__ __forceinline__ f16x8 ds_rd16(unsigned addr)
{
    f16x8 r;
    asm volatile("ds_read_b128 %0, %1" : "=v"(r) : "v"(addr));
    return r;
}

// ===========================================================================
// Fused prologue (single launch, 9281 blocks x 256 thr) — round-14 proven.
// ===========================================================================
__global__ __launch_bounds__(256)
void k_pre(const float* __restrict__ x0, f16* __restrict__ xh,
           const float* __restrict__ W, f16* __restrict__ Wh,
           const int* __restrict__ etype, int* __restrict__ flag,
           float* __restrict__ ssb)
{
    const int t = threadIdx.x;
    const int bi = blockIdx.x;
    if (bi < 8192) {
        const int xcd = bi & 7, j = bi >> 3;          // j in [0,1024)
        const int b = 2 * xcd + (j & 1);
        const int off = j >> 1;                       // [0,512) chunks/batch
        const int i = (b * 512 + off) * 256 + t;      // float4 index
        const float4 v = ((const float4*)x0)[i];
        f16x4 h; h[0] = (f16)v.x; h[1] = (f16)v.y; h[2] = (f16)v.z; h[3] = (f16)v.w;
        ((f16x4*)xh)[i] = h;
    } else if (bi < 9216) {
        const int i = (bi - 8192) * 256 + t;
        const float4 v = ((const float4*)W)[i];
        f16x4 h; h[0] = (f16)v.x; h[1] = (f16)v.y; h[2] = (f16)v.z; h[3] = (f16)v.w;
        ((f16x4*)Wh)[i] = h;
    } else if (bi == 9216) {
        if (t < 128) {
            const int b = t >> 3, kt = t & 7;
            const int* p = etype + b * S_ + kt * 128;
            int any0 = 0;
#pragma unroll
            for (int i = 0; i < 128; i += 4) {
                const int4 v = *(const int4*)(p + i);
                any0 |= (v.x == 0) | (v.y == 0) | (v.z == 0) | (v.w == 0);
            }
            flag[t] = any0;
        }
    } else {
        const int i = (bi - 9217) * 256 + t;     // 64 blocks cover 16K float4
        ((float4*)ssb)[i] = make_float4(0.f, 0.f, 0.f, 0.f);
    }
}

// ---------------------------------------------------------------------------
// 256-thread stage: 128 rows x 64 f16 (16 KB), 4 gload_lds/thread, linear
// dest + pre-swizzled global source (16B slot s of row r <- col-group
// s ^ (r&7); proven zero-conflict r10).
// ---------------------------------------------------------------------------
__device__ __forceinline__ void stage128x64(const f16* __restrict__ src, int ld,
                                            char* lds0, int t)
{
    const int r = t >> 3;                         // [0,32)
    const int c = ((t & 7) ^ (r & 7)) << 3;
    const f16* g = src + (size_t)r * ld + c;
#pragma unroll
    for (int j = 0; j < 4; ++j)                   // (r+32j)&7 == r&7
        __builtin_amdgcn_global_load_lds(AS1(g + (size_t)(32 * j) * ld),
                                         AS3(lds0 + j * 4096 + t * 16), 16, 0, 0);
}

// asm-read MMA for one K=64 step (kk-outer order preserved -> bitwise-same).
__device__ __forceinline__ void mma_asm(unsigned aB, unsigned bB,
                                        const unsigned (*offA)[2],
                                        const unsigned (*offB)[2],
                                        f32x4 (*acc)[4])
{
    f16x8 af[4][2], bf[4][2];
#pragma unroll
    for (int kk = 0; kk < 2; ++kk) {
#pragma unroll
        for (int i = 0; i < 4; ++i) af[i][kk] = ds_rd16(aB + offA[i][kk]);
#pragma unroll
        for (int j = 0; j < 4; ++j) bf[j][kk] = ds_rd16(bB + offB[j][kk]);
    }
    asm volatile("s_waitcnt lgkmcnt(0)" ::: "memory");
    __builtin_amdgcn_sched_barrier(0);            // rule #18: pin MFMA after wait
#pragma unroll
    for (int kk = 0; kk < 2; ++kk)
#pragma unroll
        for (int i = 0; i < 4; ++i)
#pragma unroll
            for (int j = 0; j < 4; ++j)
                acc[i][j] = MFMA(af[i][kk], bf[j][kk], acc[i][j], 0, 0, 0);
}

// ---------------------------------------------------------------------------
// Counted-vmcnt double-buffered GEMM, K=512 fixed (k_vs). Proven r15.
// Per step: stage(next buf) -> VMF(8) -> SBAR -> mma_asm(cur) -> SBAR.
// Ledger (8 gload_lds/stage/wave): outstanding peaks at 16; VMF(8) retires
// exactly the previously-staged buffer; SBAR makes it cross-wave; VMF(0)
// only at tail. Buffers compile-time (r4 lesson). LDS 64KB -> 2 blocks/CU.
// ---------------------------------------------------------------------------
__device__ __forceinline__ void gemm_cnt(const f16* __restrict__ A, int ldA,
                                         const f16* __restrict__ Bm, int ldB,
                                         char* lds, int t,
                                         const unsigned (*offA)[2],
                                         const unsigned (*offB)[2],
                                         f32x4 (*acc)[4])
{
    const unsigned base = (unsigned)(unsigned long long)AS3(lds);
    // X: A@+0 B@+16384 | Y: A@+32768 B@+49152
    stage128x64(A, ldA, lds, t);
    stage128x64(Bm, ldB, lds + 16384, t);
#pragma unroll 1
    for (int i = 0; i < 3; ++i) {
        const int k1 = i * 128 + 64, k2 = i * 128 + 128;
        stage128x64(A + k1, ldA, lds + 32768, t);
        stage128x64(Bm + k1, ldB, lds + 49152, t);
        VMF(8); SBAR();
        mma_asm(base, base + 16384, offA, offB, acc);        // k = 128i
        SBAR();
        stage128x64(A + k2, ldA, lds, t);
        stage128x64(Bm + k2, ldB, lds + 16384, t);
        VMF(8); SBAR();
        mma_asm(base + 32768, base + 49152, offA, offB, acc); // k = 128i+64
        SBAR();
    }
    stage128x64(A + 448, ldA, lds + 32768, t);
    stage128x64(Bm + 448, ldB, lds + 49152, t);
    VMF(8); SBAR();
    mma_asm(base, base + 16384, offA, offB, acc);             // k = 384
    SBAR();
    VMF(0); SBAR();
    mma_asm(base + 32768, base + 49152, offA, offB, acc);     // k = 448
}

// ---------------------------------------------------------------------------
// Diagonal variant (scores tiles with bk==bq): A and B are the SAME 128
// rows -> stage once per step (4 ops, VMF(4) ledger), feed both MFMA
// operands from the same buffer. Proven bitwise-identical in r10 (2-phase
// diag dedup); same counted recipe as gemm_cnt. X@0, Y@32768.
// ---------------------------------------------------------------------------
__device__ __forceinline__ void gemm_cnt_diag(const f16* __restrict__ A, int ldA,
                                              char* lds, int t,
                                              const unsigned (*offA)[2],
                                              const unsigned (*offB)[2],
                                              f32x4 (*acc)[4])
{
    const unsigned base = (unsigned)(unsigned long long)AS3(lds);
    stage128x64(A, ldA, lds, t);
#pragma unroll 1
    for (int i = 0; i < 3; ++i) {
        const int k1 = i * 128 + 64, k2 = i * 128 + 128;
        stage128x64(A + k1, ldA, lds + 32768, t);
        VMF(4); SBAR();
        mma_asm(base, base, offA, offB, acc);                 // k = 128i
        SBAR();
        stage128x64(A + k2, ldA, lds, t);
        VMF(4); SBAR();
        mma_asm(base + 32768, base + 32768, offA, offB, acc); // k = 128i+64
        SBAR();
    }
    stage128x64(A + 448, ldA, lds + 32768, t);
    VMF(4); SBAR();
    mma_asm(base, base, offA, offB, acc);                     // k = 384
    SBAR();
    VMF(0); SBAR();
    mma_asm(base + 32768, base + 32768, offA, offB, acc);     // k = 448
}

// ===========================================================================
// k_vs: round-15 proven version (counted-vmcnt, 128x128, 4 waves) + diag
// dedup for bk==bq score tiles:
//   blocks [0,1024): scores (XCD-pinned, ~44% early-exit) + fused Sum(s^2)
//   blocks [1024,1536): vT = ELU(x @ W^T + b)^T, XCD-pinned
// ===========================================================================
__global__ __launch_bounds__(256)
void k_vs(const f16* __restrict__ xh, const f16* __restrict__ Wh,
          const float* __restrict__ bias, f16* __restrict__ vT,
          const int* __restrict__ etype, const int* __restrict__ flag,
          f16* __restrict__ sh, float* __restrict__ ss)
{
    __shared__ __align__(16) char lds[65536];
    const int t = threadIdx.x;
    const int w = t >> 6, lane = t & 63, lr = lane & 15, quad = lane >> 4;
    const int wm = w & 1, wn = w >> 1;

    unsigned offA[4][2], offB[4][2];
#pragma unroll
    for (int i = 0; i < 4; ++i) {
        const int ra = wm * 64 + i * 16 + lr;
        const int rb = wn * 64 + i * 16 + lr;
#pragma unroll
        for (int kk = 0; kk < 2; ++kk) {
            offA[i][kk] = (unsigned)((ra << 7) + ((((kk << 2) + quad) ^ (ra & 7)) << 4));
            offB[i][kk] = (unsigned)((rb << 7) + ((((kk << 2) + quad) ^ (rb & 7)) << 4));
        }
    }

    if (blockIdx.x < 1024) {
        // ---------------- scores ----------------
        const int i0 = blockIdx.x;
        const int xcd = i0 & 7, j0 = i0 >> 3;          // j0 in [0,128)
        const int b = 2 * xcd + (j0 & 1);
        const int tile = j0 >> 1;                      // [0,64)
        const int bk = (tile & 7) * 128;               // keys (M)
        const int bq = (tile >> 3) * 128;              // queries (N)
        if (bk < bq && !flag[b * 8 + (bk >> 7)]) return;

        const f16* xb = xh + (size_t)b * S_ * D_;
        f32x4 acc[4][4] = {};
        if (bk == bq)
            gemm_cnt_diag(xb + (size_t)bk * D_, D_, lds, t, offA, offB, acc);
        else
            gemm_cnt(xb + (size_t)bk * D_, D_, xb + (size_t)bq * D_, D_,
                     lds, t, offA, offB, acc);
        const float sc = INV_TEMP * C_SCALE;
        float ssq[4] = {0.0f, 0.0f, 0.0f, 0.0f};
#pragma unroll
        for (int i = 0; i < 4; ++i) {
            const int k4 = bk + wm * 64 + i * 16 + quad * 4;
            const int4 et = *(const int4*)(etype + b * S_ + k4);
            const int ev[4] = {et.x, et.y, et.z, et.w};
#pragma unroll
            for (int j = 0; j < 4; ++j) {
                const int q = bq + wn * 64 + j * 16 + lr;
                f16x4 hv;
#pragma unroll
                for (int r = 0; r < 4; ++r) {
                    const bool keep = ((k4 + r) > q) || (ev[r] == 0);
                    hv[r] = (f16)(keep ? acc[i][j][r] * sc : 0.0f);
                    const float fv = (float)hv[r];
                    ssq[j] += fv * fv;               // sum of squares of STORED fp16
                }
                *(f16x4*)(sh + ((size_t)b * S_ + q) * S_ + k4) = hv;
            }
        }
#pragma unroll
        for (int j = 0; j < 4; ++j) {
            float v = ssq[j];
            v += __shfl_xor(v, 16, 64);
            v += __shfl_xor(v, 32, 64);
            if (quad == 0) {
                const int q = bq + wn * 64 + j * 16 + lr;
                atomicAdd(ss + b * S_ + q, v);
            }
        }
    } else {
        // -------- vT = ELU(x @ W^T + b)^T, XCD-pinned by batch --------
        const int idx = blockIdx.x - 1024;             // [0,512)
        const int xcd = idx & 7;
        const int b = 2 * xcd + ((idx >> 3) & 1);
        const int rest = idx >> 4;                     // [0,32)
        const int sq = rest & 7;                       // m-tile within batch
        const int bn = (rest >> 3) * 128;              // e-tile
        const int bm = b * 1024 + sq * 128;
        f32x4 acc[4][4] = {};
        gemm_cnt(xh + (size_t)bm * D_, D_, Wh + (size_t)bn * D_, D_,
                 lds, t, offA, offB, acc);
#pragma unroll
        for (int j = 0; j < 4; ++j) {
            const int e = bn + wn * 64 + j * 16 + lr;
            const float be = bias[e];
#pragma unroll
            for (int i = 0; i < 4; ++i) {
                const int s = sq * 128 + wm * 64 + i * 16 + quad * 4;
                f16x4 hv;
#pragma unroll
                for (int r = 0; r < 4; ++r) {
                    float z = acc[i][j][r] + be;
                    z = (z > 0.0f) ? z : (expf(z) - 1.0f);
                    hv[r] = (f16)z;
                }
                *(f16x4*)(vT + ((size_t)b * D_ + e) * S_ + s) = hv;
            }
        }
    }
}

// plain-deref MMA for k_out (r15 path)
__device__ __forceinline__ void mma64(const char* ldsA, const char* ldsB,
                                      int wm, int wn, int lr, int quad,
                                      f32x4 (*acc)[4])
{
#pragma unroll
    for (int kk = 0; kk < 2; ++kk) {
        f16x8 af[4], bf[4];
#pragma unroll
        for (int i = 0; i < 4; ++i) {
            const int row = wm * 64 + i * 16 + lr;
            af[i] = *(const f16x8*)(ldsA + (row << 7) +
                                    ((((kk << 2) + quad) ^ (row & 7)) << 4));
        }
#pragma unroll
        for (int j = 0; j < 4; ++j) {
            const int row = wn * 64 + j * 16 + lr;
            bf[j] = *(const f16x8*)(ldsB + (row << 7) +
                                    ((((kk << 2) + quad) ^ (row & 7)) << 4));
        }
#pragma unroll
        for (int i = 0; i < 4; ++i)
#pragma unroll
            for (int j = 0; j < 4; ++j)
                acc[i][j] = MFMA(af[i], bf[j], acc[i][j], 0, 0, 0);
    }
}

// ===========================================================================
// k_out: EXACT round-15 proven version (323.4 us config). 512 blocks x
// 512 thr (8 waves), two 4-wave K-half groups, BK=64 drain core, 128x128
// tiles. r16 lesson: the counted single-group port halved waves/CU (16->8)
// and regressed — counted-vmcnt does not substitute for TLP. Deterministic
// combine: g1 -> LDS -> g0 adds.
// ===========================================================================
__global__ __launch_bounds__(512)
void k_out(const f16* __restrict__ vT, const f16* __restrict__ sh,
           const float* __restrict__ ss, const int* __restrict__ flag,
           f16* __restrict__ xh_w,
           const f16* __restrict__ xs0, const f16* __restrict__ xs1,
           const f16* __restrict__ xs2,
           float* __restrict__ out, const int accum, const int wout)
{
    __shared__ __align__(16) char lds[65536];   // g0 @0 (A,B 16K each), g1 @32768
    __shared__ int klist[32];
    __shared__ int kcnt;
    const int t = threadIdx.x;
    const int g = t >> 8;                       // K-half group
    const int tl = t & 255;                     // thread id within group
    const int w = tl >> 6, lane = tl & 63, lr = lane & 15, quad = lane >> 4;
    const int wm = w & 1, wn = w >> 1;
    const int i0 = blockIdx.x;
    const int xcd = i0 & 7, j0 = i0 >> 3;       // j0 in [0,64)
    const int b = 2 * xcd + (j0 & 1);
    const int tile = j0 >> 1;                   // [0,32)
    const int be = (tile & 3) * 128;            // e (M), fastest
    const int bq = (tile >> 2) * 128;           // q (N)
    const int qt = bq >> 7;

    if (t == 0) {
        int n = 0;
        for (int kc = 0; kc < 8; ++kc)
            if (kc >= qt || flag[b * 8 + kc]) { // kept chunk
                const int kb = kc * 128;
                klist[n] = kb; klist[n + 1] = kb + 32;
                klist[n + 2] = kb + 64; klist[n + 3] = kb + 96;
                n += 4;
            }
        kcnt = n;                               // multiple of 4, >= 4
    }
    __syncthreads();
    const int half = kcnt >> 1;                 // even (kcnt mult of 4)
    const int s0 = g ? half : 0;

    const f16* Abase = vT + ((size_t)b * D_ + be) * S_;
    const f16* Bbase = sh + ((size_t)b * S_ + bq) * S_;
    char* myl = lds + (g << 15);
    f32x4 acc[4][4] = {};
#pragma unroll 1
    for (int i = 0; i < half; i += 2) {         // 64 contiguous cols per step
        const int k0 = klist[s0 + i];
        stage128x64(Abase + k0, S_, myl, tl);
        stage128x64(Bbase + k0, S_, myl + 16384, tl);
        __syncthreads();
        mma64(myl, myl + 16384, wm, wn, lr, quad, acc);
        __syncthreads();
    }

    // deterministic half-K combine: g1 writes its partials, g0 adds.
    if (g == 1) {
#pragma unroll
        for (int j = 0; j < 4; ++j)
#pragma unroll
            for (int i = 0; i < 4; ++i)
                *(f32x4*)(lds + (((w * 16 + j * 4 + i) * 64 + lane) << 4)) = acc[i][j];
    }
    __syncthreads();
    if (g == 0) {
#pragma unroll
        for (int j = 0; j < 4; ++j) {
            const int q = bq + wn * 64 + j * 16 + lr;
            const float ssv = ss[b * S_ + q];
            const float scl = 1.0f / (C_SCALE * fmaxf(sqrtf(ssv) * OUT_SCALE, 1e-5f));
#pragma unroll
            for (int i = 0; i < 4; ++i) {
                const f32x4 other =
                    *(const f32x4*)(lds + (((w * 16 + j * 4 + i) * 64 + lane) << 4));
                const f32x4 sum = acc[i][j] + other;
                const int e4 = be + wm * 64 + i * 16 + quad * 4;
                const size_t o = ((size_t)b * S_ + q) * D_ + e4;
                f32x4 val;
                f16x4 hx;
#pragma unroll
                for (int r = 0; r < 4; ++r) {
                    val[r] = sum[r] * scl;
                    hx[r] = (f16)val[r];
                }
                if (xh_w) *(f16x4*)(xh_w + o) = hx;
                if (xs0) {                      // final head: sum fp16 partials
                    const f16x4 a0 = *(const f16x4*)(xs0 + o);
                    const f16x4 a1 = *(const f16x4*)(xs1 + o);
                    const f16x4 a2 = *(const f16x4*)(xs2 + o);
#pragma unroll
                    for (int r = 0; r < 4; ++r)
                        val[r] += (float)a0[r] + (float)a1[r] + (float)a2[r];
                }
                if (wout) {
                    f32x4 v2 = val;
                    if (accum) { const f32x4 old = *(const f32x4*)(out + o); v2 = v2 + old; }
                    *(f32x4*)(out + o) = v2;
                }
            }
        }
    }
}

// ---------------------------------------------------------------------------
// Workspace (big mode, ~100.3 MB):
//   xA @0 (16M: conv output, then reused as xh0), vT @16M (16M),
//   sh @32M (32M), Wh @64M (2M), ss @66M (256K), flags @66M+256K,
//   xB @68M (16M: xh1), xC @84M (16M: xh2)
// Fallback (< 101 MB ws): xB=xC=xA, fp32 out RMW.
// ---------------------------------------------------------------------------
extern "C" void kernel_launch(void* const* d_in, const int* in_sizes, int n_in,
                              void* d_out, int out_size, void* d_ws, size_t ws_size,
                              hipStream_t stream) {
    const float* x0    = (const float*)d_in[0];
    const int*   etype = (const int*)d_in[2];
    const float* W     = (const float*)d_in[3];
    const float* bias  = (const float*)d_in[4];
    float* out = (float*)d_out;

    char* ws = (char*)d_ws;
    f16*   xA    = (f16*)(ws);
    f16*   vT    = (f16*)(ws + (16u << 20));
    f16*   sh    = (f16*)(ws + (32u << 20));
    f16*   Wh    = (f16*)(ws + (64u << 20));
    float* ssb   = (float*)(ws + (66u << 20));
    int*   flags = (int*)(ws + (66u << 20) + 262144);

    const bool big = ws_size >= ((size_t)101 << 20);
    f16* xB = big ? (f16*)(ws + (68u << 20)) : xA;
    f16* xC = big ? (f16*)(ws + (84u << 20)) : xA;

    // fused prologue: x conv + W conv + flags + ss zeroing in ONE launch
    k_pre<<<9281, 256, 0, stream>>>(x0, xA, W, Wh, etype, flags, ssb);

    // per-head k_vs input and k_out fp16 destination
    f16* xin[H_]  = {xA, xA, xB, xC};
    f16* xdst[H_] = {xA, xB, xC, nullptr};

    for (int h = 0; h < H_; ++h) {
        float* ss = ssb + (size_t)h * B_ * S_;
        k_vs <<<1536, 256, 0, stream>>>(xin[h], Wh + (size_t)h * D_ * D_,
                                        bias + (size_t)h * D_, vT,
                                        etype, flags, sh, ss);
        if (big) {
            const bool last = (h == H_ - 1);
            k_out<<<512, 512, 0, stream>>>(vT, sh, ss, flags, xdst[h],
                                           last ? xA : nullptr,
                                           last ? xB : nullptr,
                                           last ? xC : nullptr,
                                           out, 0, last ? 1 : 0);
        } else {
            k_out<<<512, 512, 0, stream>>>(vT, sh, ss, flags,
                                           (h < H_ - 1) ? xA : nullptr,
                                           nullptr, nullptr, nullptr,
                                           out, h > 0, 1);
        }
    }
}